// Round 6
// baseline (168.020 us; speedup 1.0000x reference)
//
#include <hip/hip_runtime.h>

constexpr int N_NODES  = 50000;
constexpr int N_EDGES  = 1600000;
constexpr int F_IN     = 48;
constexpr int C1_OUT   = 16;

// ---- binning geometry -----------------------------------------------------
constexpr int BNODES    = 64;                     // nodes per bin; bin = dst >> 6
constexpr int NBINS     = 782;                    // ceil(50000/64)
constexpr int FILL_BLKS = 256;
constexpr int EPB       = N_EDGES / FILL_BLKS;    // 6250 (exact)
constexpr int SCAP      = 16;                     // slots/cell = exactly one 64B line
constexpr int OCAP      = 16384;                  // overflow list (expected ~1000)
constexpr int BIN_INTS  = FILL_BLKS * SCAP;       // 4096 ints per bin (16 KB)
constexpr int ROWCAP    = 96;                     // per-node row; P(deg>96) ~ 1e-18
constexpr int XW_BLKS   = 49;                     // 49*1024 >= 50000

// ---- workspace layout (~16.1 MB of ~256 MB ws) -----------------------------
constexpr size_t OCNT_OFF  = 0;
constexpr size_t OFLOW_OFF = 256;
constexpr size_t PART_OFF  = OFLOW_OFF + (size_t)OCAP * 4;
constexpr size_t XW_OFF    = PART_OFF + 4096;
constexpr size_t GSLOT_OFF = XW_OFF + (size_t)N_NODES * C1_OUT * 4;

// ---------------------------------------------------------------------------
// xw[n] = x[n] @ W  (fold linear map before gather; 3.2 MB table)
// ---------------------------------------------------------------------------
__device__ __forceinline__ void xw_body(int n, const float* __restrict__ x,
                                        const float* __restrict__ W,
                                        float* __restrict__ xw)
{
    const float4* xr = (const float4*)(x + (long)n * F_IN);
    float h[C1_OUT];
    #pragma unroll
    for (int c = 0; c < C1_OUT; ++c) h[c] = 0.f;
    #pragma unroll
    for (int k = 0; k < F_IN / 4; ++k) {
        float4 v = xr[k];
        #pragma unroll
        for (int c = 0; c < C1_OUT; ++c) {
            h[c] = fmaf(v.x, W[(4*k+0)*C1_OUT + c],
                   fmaf(v.y, W[(4*k+1)*C1_OUT + c],
                   fmaf(v.z, W[(4*k+2)*C1_OUT + c],
                   fmaf(v.w, W[(4*k+3)*C1_OUT + c], h[c]))));
        }
    }
    float4* o = (float4*)(xw + (long)n * C1_OUT);
    o[0] = make_float4(h[0],  h[1],  h[2],  h[3]);
    o[1] = make_float4(h[4],  h[5],  h[6],  h[7]);
    o[2] = make_float4(h[8],  h[9],  h[10], h[11]);
    o[3] = make_float4(h[12], h[13], h[14], h[15]);
}

// ---------------------------------------------------------------------------
// Pass 1: LDS-staged binning, FULL-LINE flush. Zero global atomics.
// Phase 1: stage edge (src<<6)|(dst&63) into lstage[bin][slot] (LDS).
// Phase 2: flush EVERY cell as a complete 64B line (valid + -1 padding).
//   -> every cell fully written each run (re-poison safe, no memset, no cnt
//      table), and stores are line-granular: 200K line transactions instead
//      of 1.6M scattered 4B transactions (R5's 44us / 1.9x-amplified WRITE).
// xw fused in a disjoint block range.
// ---------------------------------------------------------------------------
__global__ __launch_bounds__(1024)
void k_fill_xw(const int* __restrict__ src, const int* __restrict__ dst,
               int* __restrict__ gslot, int* __restrict__ ocnt,
               unsigned int* __restrict__ oflow,
               const float* __restrict__ x, const float* __restrict__ W,
               float* __restrict__ xw)
{
    __shared__ int lcnt[NBINS];
    __shared__ int lstage[NBINS * SCAP];          // 50 KB

    if (blockIdx.x >= FILL_BLKS) {                // fused xw range
        int n = (blockIdx.x - FILL_BLKS) * 1024 + threadIdx.x;
        if (n < N_NODES) xw_body(n, x, W, xw);
        return;
    }

    int tid = threadIdx.x;
    if (tid < NBINS) lcnt[tid] = 0;
    __syncthreads();

    int e0 = blockIdx.x * EPB;
    for (int i = tid; i < EPB; i += 1024) {
        int e = e0 + i;
        int s = src[e], d = dst[e];
        int b = d >> 6;
        int p = atomicAdd(&lcnt[b], 1);
        if (p < SCAP) {
            lstage[(b << 4) + p] = (s << 6) | (d & 63);
        } else {                                   // ~1000 edges expected total
            int g = atomicAdd(ocnt, 1);
            if (g < OCAP) oflow[g] = ((unsigned)s << 16) | (unsigned)d;
        }
    }
    __syncthreads();

    // flush: one slot per thread; 16 consecutive threads = one full 64B line
    for (int idx = tid; idx < NBINS * SCAP; idx += 1024) {
        int b = idx >> 4, s = idx & 15;
        int v = (s < lcnt[b]) ? lstage[idx] : -1;
        gslot[((size_t)b * FILL_BLKS + blockIdx.x) * SCAP + s] = v;
    }
}

// ---------------------------------------------------------------------------
// Pass 2: one block (256 thr, 4 waves) per 64-node bin.
//   A: blind coalesced int4 read of the bin's 4096 slots (16 KB); -1 skipped.
//   B: direct scatter into fixed per-node LDS rows lrow[64][96] — ONE int
//      atomic + ONE ds_write per edge (no hist, no scan, 2 fewer barriers
//      than the CSR rebuild).
//   C: wave-per-node register aggregation + shuffle reduce + fused epilogue.
// LDS ~12.8 KB -> thread-bound 8 blocks/CU.
// ---------------------------------------------------------------------------
__device__ __forceinline__ float node_epilogue(
    float4 a, int n, float inv, const float* __restrict__ xw,
    const float* __restrict__ bias, const float* __restrict__ lin1_w,
    const float* __restrict__ lin1_b, const float* __restrict__ out_w,
    const float* __restrict__ out_b, const float* __restrict__ labels,
    const float* __restrict__ weights, float* __restrict__ out,
    float* s16, int lane)
{
    if (lane < 4) {
        float4 v  = ((const float4*)(xw + (size_t)n * C1_OUT))[lane]; // self loop
        float4 b4 = ((const float4*)bias)[lane];
        float4 h;
        h.x = fmaxf(fmaf(a.x + v.x, inv, b4.x), 0.f);
        h.y = fmaxf(fmaf(a.y + v.y, inv, b4.y), 0.f);
        h.z = fmaxf(fmaf(a.z + v.z, inv, b4.z), 0.f);
        h.w = fmaxf(fmaf(a.w + v.w, inv, b4.w), 0.f);
        ((float4*)s16)[lane] = h;
    }
    float x2 = 0.f;
    if (lane < 8) {
        x2 = lin1_b[lane];
        #pragma unroll
        for (int k = 0; k < C1_OUT; ++k)
            x2 = fmaf(s16[k], lin1_w[k * 8 + lane], x2);
        x2 = fmaxf(x2, 0.f) * out_w[lane];
    }
    x2 += __shfl_xor(x2, 1, 64);
    x2 += __shfl_xor(x2, 2, 64);
    x2 += __shfl_xor(x2, 4, 64);
    float ret = 0.f;
    if (lane == 0) {
        float z = x2 + out_b[0];
        float p = 1.f / (1.f + __expf(-z));
        out[1 + n] = p;
        const float eps = 1e-7f;
        float pc = fminf(fmaxf(p, eps), 1.f - eps);
        float y  = labels[n];
        ret = weights[n] * (-(y * __logf(pc) + (1.f - y) * __logf(1.f - pc)));
    }
    return ret;
}

__global__ __launch_bounds__(256)
void k_agg(const int* __restrict__ gslot, const int* __restrict__ ocnt,
           const unsigned int* __restrict__ oflow, const float* __restrict__ xw,
           const float* __restrict__ bias, const float* __restrict__ lin1_w,
           const float* __restrict__ lin1_b, const float* __restrict__ out_w,
           const float* __restrict__ out_b, const float* __restrict__ labels,
           const float* __restrict__ weights, float* __restrict__ out,
           float* __restrict__ partials)
{
    __shared__ int ndeg[BNODES];
    __shared__ unsigned short lrow[BNODES][ROWCAP];   // 12 KB
    __shared__ float s16[4][16];
    __shared__ float sLossW[4];

    int B = blockIdx.x, tid = threadIdx.x, lane = tid & 63, w = tid >> 6;

    if (tid < BNODES) ndeg[tid] = 0;
    __syncthreads();

    // A+B: stream the bin's 4096 slots, scatter valid edges into node rows
    const int4* sp = (const int4*)(gslot + (size_t)B * BIN_INTS);
    #pragma unroll
    for (int k = 0; k < 4; ++k) {
        int4 q = sp[tid + (k << 8)];
        #define SC1(v) if ((v) >= 0) { int ln = (v) & 63;               \
            int p = atomicAdd(&ndeg[ln], 1);                            \
            if (p < ROWCAP) lrow[ln][p] = (unsigned short)((unsigned)(v) >> 6); }
        SC1(q.x); SC1(q.y); SC1(q.z); SC1(q.w);
        #undef SC1
    }
    int oc = *ocnt; if (oc > OCAP) oc = OCAP;
    for (int i = tid; i < oc; i += 256) {
        unsigned v = oflow[i];
        int d = (int)(v & 0xffffu);
        if ((d >> 6) == B) {
            int ln = d & 63;
            int p = atomicAdd(&ndeg[ln], 1);
            if (p < ROWCAP) lrow[ln][p] = (unsigned short)(v >> 16);
        }
    }
    __syncthreads();

    // C: wave-per-node register aggregation; 4 waves x 16 nodes
    int rslot = lane >> 2, c4 = lane & 3;
    float lossw = 0.f;
    for (int i = 0; i < 16; ++i) {
        int ln = w * 16 + i;
        int n = B * BNODES + ln;
        if (n >= N_NODES) break;                  // wave-uniform
        int deg = ndeg[ln];
        if (deg > ROWCAP) deg = ROWCAP;           // safety; P ~ 1e-18
        float4 a = make_float4(0.f, 0.f, 0.f, 0.f);
        for (int j0 = 0; j0 < deg; j0 += 16) {
            int j = j0 + rslot;
            if (j < deg) {
                int s = lrow[ln][j];
                float4 v = ((const float4*)(xw + (size_t)s * C1_OUT))[c4];
                a.x += v.x; a.y += v.y; a.z += v.z; a.w += v.w;
            }
        }
        #pragma unroll
        for (int off = 4; off < 64; off <<= 1) {
            a.x += __shfl_xor(a.x, off, 64);
            a.y += __shfl_xor(a.y, off, 64);
            a.z += __shfl_xor(a.z, off, 64);
            a.w += __shfl_xor(a.w, off, 64);
        }
        lossw += node_epilogue(a, n, 1.f / (float)(deg + 1), xw, bias, lin1_w,
                               lin1_b, out_w, out_b, labels, weights, out,
                               s16[w], lane);
    }
    if (lane == 0) sLossW[w] = lossw;
    __syncthreads();
    if (tid == 0)
        partials[B] = sLossW[0] + sLossW[1] + sLossW[2] + sLossW[3];
}

// ---------------------------------------------------------------------------
// Final loss reduce: one block over 782 partials.
// ---------------------------------------------------------------------------
__global__ __launch_bounds__(1024)
void k_loss_final(const float* __restrict__ partials, float* __restrict__ out)
{
    __shared__ float sw[16];
    int tid = threadIdx.x, lane = tid & 63, wv = tid >> 6;
    float s = (tid < NBINS) ? partials[tid] : 0.f;
    #pragma unroll
    for (int off = 32; off > 0; off >>= 1) s += __shfl_down(s, off, 64);
    if (lane == 0) sw[wv] = s;
    __syncthreads();
    if (tid == 0) {
        float t = 0.f;
        #pragma unroll
        for (int k = 0; k < 16; ++k) t += sw[k];
        out[0] = t / (float)N_NODES;
    }
}

// ===========================================================================
extern "C" void kernel_launch(void* const* d_in, const int* in_sizes, int n_in,
                              void* d_out, int out_size, void* d_ws, size_t ws_size,
                              hipStream_t stream)
{
    const float* x       = (const float*)d_in[0];
    const int*   eidx    = (const int*)  d_in[1];   // [2, E]
    const float* labels  = (const float*)d_in[2];
    const float* weights = (const float*)d_in[3];
    const float* W       = (const float*)d_in[4];
    // d_in[5] = u, d_in[6] = c: dead — softmax over H=1 axis is identically 1
    const float* bias    = (const float*)d_in[7];
    const float* lin1_w  = (const float*)d_in[8];
    const float* lin1_b  = (const float*)d_in[9];
    const float* out_w   = (const float*)d_in[10];
    const float* out_b   = (const float*)d_in[11];
    float* out = (float*)d_out;

    const int* src = eidx;
    const int* dst = eidx + N_EDGES;
    char* ws = (char*)d_ws;

    int*          ocnt     = (int*)(ws + OCNT_OFF);
    unsigned int* oflow    = (unsigned int*)(ws + OFLOW_OFF);
    float*        partials = (float*)(ws + PART_OFF);
    float*        xw       = (float*)(ws + XW_OFF);
    int*          gslot    = (int*)(ws + GSLOT_OFF);

    hipMemsetAsync(ocnt, 0, sizeof(int), stream);
    k_fill_xw<<<FILL_BLKS + XW_BLKS, 1024, 0, stream>>>(
        src, dst, gslot, ocnt, oflow, x, W, xw);
    k_agg<<<NBINS, 256, 0, stream>>>(
        gslot, ocnt, oflow, xw, bias, lin1_w, lin1_b,
        out_w, out_b, labels, weights, out, partials);
    k_loss_final<<<1, 1024, 0, stream>>>(partials, out);
}

// Round 7
// 138.115 us; speedup vs baseline: 1.2165x; 1.2165x over previous
//
#include <hip/hip_runtime.h>

constexpr int N_NODES  = 50000;
constexpr int N_EDGES  = 1600000;
constexpr int F_IN     = 48;
constexpr int C1_OUT   = 16;

// ---- binning geometry -----------------------------------------------------
constexpr int BNODES    = 64;                     // nodes per bin; bin = dst >> 6
constexpr int NBINS     = 782;                    // ceil(50000/64)
constexpr int FILL_BLKS = 256;
constexpr int EPB       = N_EDGES / FILL_BLKS;    // 6250 (exact)
constexpr int SCAP      = 16;                     // slots/cell = exactly one 64B line
constexpr int OCAP      = 16384;                  // overflow list (expected ~1000)
constexpr int BIN_INTS  = FILL_BLKS * SCAP;       // 4096 ints per bin (16 KB)
constexpr int ROWCAP    = 98;                     // per-node row; 49 dwords (odd) ->
                                                  // row bases cycle all 32 banks
constexpr int XW_BLKS   = 49;                     // 49*1024 >= 50000

// ---- workspace layout (~16.1 MB of ~256 MB ws) -----------------------------
constexpr size_t OCNT_OFF  = 0;
constexpr size_t OFLOW_OFF = 256;
constexpr size_t PART_OFF  = OFLOW_OFF + (size_t)OCAP * 4;
constexpr size_t XW_OFF    = PART_OFF + 4096;
constexpr size_t GSLOT_OFF = XW_OFF + (size_t)N_NODES * C1_OUT * 4;

// ---------------------------------------------------------------------------
// xw[n] = x[n] @ W  (fold linear map before gather; 3.2 MB table)
// ---------------------------------------------------------------------------
__device__ __forceinline__ void xw_body(int n, const float* __restrict__ x,
                                        const float* __restrict__ W,
                                        float* __restrict__ xw)
{
    const float4* xr = (const float4*)(x + (long)n * F_IN);
    float h[C1_OUT];
    #pragma unroll
    for (int c = 0; c < C1_OUT; ++c) h[c] = 0.f;
    #pragma unroll
    for (int k = 0; k < F_IN / 4; ++k) {
        float4 v = xr[k];
        #pragma unroll
        for (int c = 0; c < C1_OUT; ++c) {
            h[c] = fmaf(v.x, W[(4*k+0)*C1_OUT + c],
                   fmaf(v.y, W[(4*k+1)*C1_OUT + c],
                   fmaf(v.z, W[(4*k+2)*C1_OUT + c],
                   fmaf(v.w, W[(4*k+3)*C1_OUT + c], h[c]))));
        }
    }
    float4* o = (float4*)(xw + (long)n * C1_OUT);
    o[0] = make_float4(h[0],  h[1],  h[2],  h[3]);
    o[1] = make_float4(h[4],  h[5],  h[6],  h[7]);
    o[2] = make_float4(h[8],  h[9],  h[10], h[11]);
    o[3] = make_float4(h[12], h[13], h[14], h[15]);
}

// ---------------------------------------------------------------------------
// Pass 1 (UNCHANGED from R6 — measured ~10us): LDS-staged binning, full-line
// flush, zero global atomics, re-poison-safe without memset.
// ---------------------------------------------------------------------------
__global__ __launch_bounds__(1024)
void k_fill_xw(const int* __restrict__ src, const int* __restrict__ dst,
               int* __restrict__ gslot, int* __restrict__ ocnt,
               unsigned int* __restrict__ oflow,
               const float* __restrict__ x, const float* __restrict__ W,
               float* __restrict__ xw)
{
    __shared__ int lcnt[NBINS];
    __shared__ int lstage[NBINS * SCAP];          // 50 KB

    if (blockIdx.x >= FILL_BLKS) {                // fused xw range
        int n = (blockIdx.x - FILL_BLKS) * 1024 + threadIdx.x;
        if (n < N_NODES) xw_body(n, x, W, xw);
        return;
    }

    int tid = threadIdx.x;
    if (tid < NBINS) lcnt[tid] = 0;
    __syncthreads();

    int e0 = blockIdx.x * EPB;
    for (int i = tid; i < EPB; i += 1024) {
        int e = e0 + i;
        int s = src[e], d = dst[e];
        int b = d >> 6;
        int p = atomicAdd(&lcnt[b], 1);
        if (p < SCAP) {
            lstage[(b << 4) + p] = (s << 6) | (d & 63);
        } else {                                   // ~1000 edges expected total
            int g = atomicAdd(ocnt, 1);
            if (g < OCAP) oflow[g] = ((unsigned)s << 16) | (unsigned)d;
        }
    }
    __syncthreads();

    // flush: one slot per thread; 16 consecutive threads = one full 64B line
    for (int idx = tid; idx < NBINS * SCAP; idx += 1024) {
        int b = idx >> 4, s = idx & 15;
        int v = (s < lcnt[b]) ? lstage[idx] : -1;
        gslot[((size_t)b * FILL_BLKS + blockIdx.x) * SCAP + s] = v;
    }
}

// ---------------------------------------------------------------------------
// Pass 2: one block (256 thr, 4 waves) per 64-node bin.
//   A: blind coalesced int4 read of the bin's 4096 slots.
//   B: direct scatter into lrow[64][98] (odd-dword stride -> bank-clean).
//   C: wave-per-node-PAIR register gather (2 independent accumulate+reduce
//      chains for ILP); reduced sums go to acc[64][17] — NO epilogue here.
//   D: thread-per-node epilogue (lane<16, all 4 waves in parallel) — the 16
//      serial ~500-cycle epilogue chains per wave of R6 become 1.
// No barrier between C and D: each wave reads only acc rows it wrote
// (same-wave DS ordering).
// ---------------------------------------------------------------------------
__global__ __launch_bounds__(256)
void k_agg(const int* __restrict__ gslot, const int* __restrict__ ocnt,
           const unsigned int* __restrict__ oflow, const float* __restrict__ xw,
           const float* __restrict__ bias, const float* __restrict__ lin1_w,
           const float* __restrict__ lin1_b, const float* __restrict__ out_w,
           const float* __restrict__ out_b, const float* __restrict__ labels,
           const float* __restrict__ weights, float* __restrict__ out,
           float* __restrict__ partials)
{
    __shared__ int ndeg[BNODES];
    __shared__ unsigned short lrow[BNODES][ROWCAP];   // 12.25 KB
    __shared__ float acc[BNODES][17];                 // pad 17 -> conflict-free
    __shared__ float sLossW[4];

    int B = blockIdx.x, tid = threadIdx.x, lane = tid & 63, w = tid >> 6;

    if (tid < BNODES) ndeg[tid] = 0;
    __syncthreads();

    // A: blind coalesced load of the bin's 4096 slots (1024 int4)
    const int4* sp = (const int4*)(gslot + (size_t)B * BIN_INTS);
    int4 q0 = sp[tid], q1 = sp[tid + 256], q2 = sp[tid + 512], q3 = sp[tid + 768];

    int oc = *ocnt; if (oc > OCAP) oc = OCAP;

    // B: scatter valid edges into per-node rows
    #define SC1(v) if ((v) >= 0) { int ln = (v) & 63;               \
        int p = atomicAdd(&ndeg[ln], 1);                            \
        if (p < ROWCAP) lrow[ln][p] = (unsigned short)((unsigned)(v) >> 6); }
    SC1(q0.x); SC1(q0.y); SC1(q0.z); SC1(q0.w);
    SC1(q1.x); SC1(q1.y); SC1(q1.z); SC1(q1.w);
    SC1(q2.x); SC1(q2.y); SC1(q2.z); SC1(q2.w);
    SC1(q3.x); SC1(q3.y); SC1(q3.z); SC1(q3.w);
    #undef SC1
    for (int i = tid; i < oc; i += 256) {
        unsigned v = oflow[i];
        int d = (int)(v & 0xffffu);
        if ((d >> 6) == B) {
            int ln = d & 63;
            int p = atomicAdd(&ndeg[ln], 1);
            if (p < ROWCAP) lrow[ln][p] = (unsigned short)(v >> 16);
        }
    }
    __syncthreads();

    // C: gather, two nodes at a time per wave
    int rslot = lane >> 2, c4 = lane & 3;
    #pragma unroll
    for (int i = 0; i < 16; i += 2) {
        int ln0 = w * 16 + i, ln1 = ln0 + 1;
        int d0 = ndeg[ln0]; if (d0 > ROWCAP) d0 = ROWCAP;
        int d1 = ndeg[ln1]; if (d1 > ROWCAP) d1 = ROWCAP;
        int m = (d0 > d1) ? d0 : d1;
        float4 a0 = make_float4(0.f, 0.f, 0.f, 0.f);
        float4 a1 = make_float4(0.f, 0.f, 0.f, 0.f);
        for (int j0 = 0; j0 < m; j0 += 16) {
            int j = j0 + rslot;
            if (j < d0) {
                int s = lrow[ln0][j];
                float4 v = ((const float4*)(xw + (size_t)s * C1_OUT))[c4];
                a0.x += v.x; a0.y += v.y; a0.z += v.z; a0.w += v.w;
            }
            if (j < d1) {
                int s = lrow[ln1][j];
                float4 v = ((const float4*)(xw + (size_t)s * C1_OUT))[c4];
                a1.x += v.x; a1.y += v.y; a1.z += v.z; a1.w += v.w;
            }
        }
        #pragma unroll
        for (int off = 4; off < 64; off <<= 1) {      // two independent chains
            a0.x += __shfl_xor(a0.x, off, 64);
            a1.x += __shfl_xor(a1.x, off, 64);
            a0.y += __shfl_xor(a0.y, off, 64);
            a1.y += __shfl_xor(a1.y, off, 64);
            a0.z += __shfl_xor(a0.z, off, 64);
            a1.z += __shfl_xor(a1.z, off, 64);
            a0.w += __shfl_xor(a0.w, off, 64);
            a1.w += __shfl_xor(a1.w, off, 64);
        }
        if (lane < 8) {                               // lanes 0-3: ln0, 4-7: ln1
            int ln = (lane < 4) ? ln0 : ln1;
            float4 a = (lane < 4) ? a0 : a1;
            int c = lane & 3;
            acc[ln][c * 4 + 0] = a.x;
            acc[ln][c * 4 + 1] = a.y;
            acc[ln][c * 4 + 2] = a.z;
            acc[ln][c * 4 + 3] = a.w;
        }
    }

    // D: thread-per-node epilogue; wave reads only its own acc rows
    float lossw = 0.f;
    if (lane < 16) {
        int ln = w * 16 + lane;
        int n = B * BNODES + ln;
        if (n < N_NODES) {
            int dg = ndeg[ln]; if (dg > ROWCAP) dg = ROWCAP;
            float inv = 1.f / (float)(dg + 1);        // +1 = self loop
            const float4* xs4 = (const float4*)(xw + (size_t)n * C1_OUT);
            float xs[16];
            ((float4*)xs)[0] = xs4[0]; ((float4*)xs)[1] = xs4[1];
            ((float4*)xs)[2] = xs4[2]; ((float4*)xs)[3] = xs4[3];
            float h[16];
            #pragma unroll
            for (int c = 0; c < 16; ++c)
                h[c] = fmaxf(fmaf(acc[ln][c] + xs[c], inv, bias[c]), 0.f);
            float z = out_b[0];
            #pragma unroll
            for (int j = 0; j < 8; ++j) {
                float t = lin1_b[j];
                #pragma unroll
                for (int k = 0; k < 16; ++k) t = fmaf(h[k], lin1_w[k * 8 + j], t);
                z = fmaf(fmaxf(t, 0.f), out_w[j], z);
            }
            float p = 1.f / (1.f + __expf(-z));
            out[1 + n] = p;
            const float eps = 1e-7f;
            float pc = fminf(fmaxf(p, eps), 1.f - eps);
            float y  = labels[n];
            lossw = weights[n] * (-(y * __logf(pc) + (1.f - y) * __logf(1.f - pc)));
        }
    }
    lossw += __shfl_xor(lossw, 1, 64);
    lossw += __shfl_xor(lossw, 2, 64);
    lossw += __shfl_xor(lossw, 4, 64);
    lossw += __shfl_xor(lossw, 8, 64);
    if (lane == 0) sLossW[w] = lossw;
    __syncthreads();
    if (tid == 0)
        partials[B] = sLossW[0] + sLossW[1] + sLossW[2] + sLossW[3];
}

// ---------------------------------------------------------------------------
// Final loss reduce: one block over 782 partials.
// ---------------------------------------------------------------------------
__global__ __launch_bounds__(1024)
void k_loss_final(const float* __restrict__ partials, float* __restrict__ out)
{
    __shared__ float sw[16];
    int tid = threadIdx.x, lane = tid & 63, wv = tid >> 6;
    float s = (tid < NBINS) ? partials[tid] : 0.f;
    #pragma unroll
    for (int off = 32; off > 0; off >>= 1) s += __shfl_down(s, off, 64);
    if (lane == 0) sw[wv] = s;
    __syncthreads();
    if (tid == 0) {
        float t = 0.f;
        #pragma unroll
        for (int k = 0; k < 16; ++k) t += sw[k];
        out[0] = t / (float)N_NODES;
    }
}

// ===========================================================================
extern "C" void kernel_launch(void* const* d_in, const int* in_sizes, int n_in,
                              void* d_out, int out_size, void* d_ws, size_t ws_size,
                              hipStream_t stream)
{
    const float* x       = (const float*)d_in[0];
    const int*   eidx    = (const int*)  d_in[1];   // [2, E]
    const float* labels  = (const float*)d_in[2];
    const float* weights = (const float*)d_in[3];
    const float* W       = (const float*)d_in[4];
    // d_in[5] = u, d_in[6] = c: dead — softmax over H=1 axis is identically 1
    const float* bias    = (const float*)d_in[7];
    const float* lin1_w  = (const float*)d_in[8];
    const float* lin1_b  = (const float*)d_in[9];
    const float* out_w   = (const float*)d_in[10];
    const float* out_b   = (const float*)d_in[11];
    float* out = (float*)d_out;

    const int* src = eidx;
    const int* dst = eidx + N_EDGES;
    char* ws = (char*)d_ws;

    int*          ocnt     = (int*)(ws + OCNT_OFF);
    unsigned int* oflow    = (unsigned int*)(ws + OFLOW_OFF);
    float*        partials = (float*)(ws + PART_OFF);
    float*        xw       = (float*)(ws + XW_OFF);
    int*          gslot    = (int*)(ws + GSLOT_OFF);

    hipMemsetAsync(ocnt, 0, sizeof(int), stream);
    k_fill_xw<<<FILL_BLKS + XW_BLKS, 1024, 0, stream>>>(
        src, dst, gslot, ocnt, oflow, x, W, xw);
    k_agg<<<NBINS, 256, 0, stream>>>(
        gslot, ocnt, oflow, xw, bias, lin1_w, lin1_b,
        out_w, out_b, labels, weights, out, partials);
    k_loss_final<<<1, 1024, 0, stream>>>(partials, out);
}